// Round 17
// baseline (455.414 us; speedup 1.0000x reference)
//
#include <hip/hip_runtime.h>
#include <hip/hip_bf16.h>
#include <stdint.h>

#define DEV __device__ __forceinline__
#define WAITV(n) asm volatile("s_waitcnt vmcnt(" #n ")" ::: "memory")
#define WAITL(n) asm volatile("s_waitcnt lgkmcnt(" #n ")" ::: "memory")
#define SCHEDB __builtin_amdgcn_sched_barrier(0)

typedef __attribute__((ext_vector_type(4))) float f32x4;
typedef __attribute__((ext_vector_type(8))) short bf16x8;
typedef unsigned short u16;

constexpr int Bb = 4, Tt = 2048, Ccn = 2048, NHn = 16, HDn = 128;
constexpr int MM = Bb * Tt;          // 8192
constexpr int NQKV = 3 * Ccn;        // 6144
constexpr int KD = 2048;             // K dim for BOTH GEMMs
constexpr size_t K2 = (size_t)KD * 2;  // row stride bytes
constexpr size_t HKB = 128 * K2;       // half-tile row block bytes
// q scale folded with log2(e): S = (q.k)/sqrt(128) * log2(e), softmax in
// exp2 domain (v_exp_f32 is base-2; saves one v_mul per exp on the VALU
// critical path).
constexpr float QSCALE2 = 0.08838834764831845f * 1.4426950408889634f;

DEV u16 f2bf(float f) {
  __hip_bfloat16 h = __float2bfloat16(f);
  return *reinterpret_cast<u16*>(&h);
}

DEV void gl_lds16(const void* g, void* l) {
  __builtin_amdgcn_global_load_lds(
      (const __attribute__((address_space(1))) void*)g,
      (__attribute__((address_space(3))) void*)l, 16, 0, 0);
}

// ---------------- merged prep kernel ----------------
__global__ void k_prep(const float* __restrict__ x, u16* __restrict__ xb,
                       const float* __restrict__ Wqkv, u16* __restrict__ WqkvT,
                       const float* __restrict__ Wproj, u16* __restrict__ WprojT,
                       float* __restrict__ ct, float* __restrict__ st) {
  __shared__ u16 tile[64][72];
  const int bid = blockIdx.x, tid = threadIdx.x;
  if (bid < 1024) {
    const int n4 = (MM * Ccn) >> 2;
    for (int idx = bid * 256 + tid; idx < n4; idx += 1024 * 256) {
      float4 v = ((const float4*)x)[idx];
      ushort4 o;
      o.x = f2bf(v.x); o.y = f2bf(v.y); o.z = f2bf(v.z); o.w = f2bf(v.w);
      ((ushort4*)xb)[idx] = o;
    }
  } else if (bid < 5120) {
    const float* in; u16* out; int NC, bx, by;
    if (bid < 4096) {
      int t = bid - 1024; in = Wqkv; out = WqkvT; NC = NQKV; bx = t % 96; by = t / 96;
    } else {
      int t = bid - 4096; in = Wproj; out = WprojT; NC = Ccn; bx = t & 31; by = t >> 5;
    }
    const int R = 2048;
    int tr = by * 64, tc = bx * 64;
    int r = tid >> 2, c = (tid & 3) * 16;
    const float* src = in + (size_t)(tr + r) * NC + tc + c;
#pragma unroll
    for (int i = 0; i < 16; i++) tile[r][c + i] = f2bf(src[i]);
    __syncthreads();
    u16* dst = out + (size_t)(tc + r) * R + tr + c;
#pragma unroll
    for (int i = 0; i < 16; i++) dst[i] = tile[c + i][r];
  } else {
    int idx = (bid - 5120) * 256 + tid;   // < 131072 = Tt*64
    int t = idx >> 6, j = idx & 63;
    float invf = expf(-(float)j * 0.14391157f);  // ln(10000)/64
    float a = (float)t * invf;
    ct[idx] = cosf(a);
    st[idx] = sinf(a);
  }
}

// ---------------- 256x256 8-phase GEMM, ks-split register pipeline -------
// (R11 config, 195us QKV / 48.6% MfmaUtil — frozen; MODE 0 epilogue uses
// QSCALE2 = QSCALE*log2e so attn softmax runs in exp2 domain)

template <int MODE>
__global__ __launch_bounds__(512, 2) void k_gemm256(
    const u16* __restrict__ A, const u16* __restrict__ Bt,
    int Ndim, int NBX,
    const float* __restrict__ bias,
    u16* __restrict__ q_r, u16* __restrict__ k_r, u16* __restrict__ vt,
    const float* __restrict__ ctab, const float* __restrict__ stab,
    float* __restrict__ outp) {
  __shared__ __align__(16) u16 SM[65536];   // 128KB: A 64KB | B 64KB
  const int tid = threadIdx.x;
  const int w = tid >> 6, lane = tid & 63;
  const int l16 = lane & 15, l4 = lane >> 4;
  const int wr = w >> 2, wc = w & 3;
  const int bid = blockIdx.x, nwg = gridDim.x;
  const int swz = (bid & 7) * (nwg >> 3) + (bid >> 3);   // XCD-aware
  const int by = swz / NBX, bx = swz % NBX;
  const int m0 = by * 256, n0 = bx * 256;
  constexpr int NT = KD >> 6;      // 32
  constexpr int NIT = NT >> 1;     // 16

  const int Mx = (l16 & 7) << 4;
  const int b6 = Mx & 64;
  const int lane_lo = l16 * 128 + ((l4 * 16) ^ (Mx & 48));
  const char* const pA0 = (const char*)SM + wr * 16384 + lane_lo + b6;
  const char* const pA1 = (const char*)SM + wr * 16384 + lane_lo + (64 - b6);
  const char* const pB0 = (const char*)SM + 65536 + (wc >> 1) * 16384 + (wc & 1) * 8192 + lane_lo + b6;
  const char* const pB1 = (const char*)SM + 65536 + (wc >> 1) * 16384 + (wc & 1) * 8192 + lane_lo + (64 - b6);

  uint32_t soff[2];
#pragma unroll
  for (int i = 0; i < 2; i++) {
    int op = i * 8192 + tid * 16;
    int ol = op ^ (((op >> 7) & 7) << 4);
    int row = ol >> 7, colb = ol & 127;
    soff[i] = (uint32_t)(row * (int)K2 + colb);
  }
  const char* const Ab = (const char*)A + (size_t)m0 * K2;
  const char* const Bbp = (const char*)Bt + (size_t)n0 * K2;
  char* const dstBase = (char*)SM;

  auto stA = [&](int buf, int half, int kt) {
#pragma unroll
    for (int i = 0; i < 2; i++)
      gl_lds16(Ab + (size_t)half * HKB + (size_t)kt * 128 + soff[i],
               dstBase + buf * 32768 + half * 16384 + i * 8192 + tid * 16);
  };
  auto stB = [&](int buf, int half, int kt) {
#pragma unroll
    for (int i = 0; i < 2; i++)
      gl_lds16(Bbp + (size_t)half * HKB + (size_t)kt * 128 + soff[i],
               dstBase + 65536 + buf * 32768 + half * 16384 + i * 8192 + tid * 16);
  };

  bf16x8 af[2][2][2];   // [parity][dm][ks]
  bf16x8 bfr[4][2];     // [nj][ks] single-buffered
  f32x4 acc[8][4];
  const f32x4 zf = {0.f, 0.f, 0.f, 0.f};
#pragma unroll
  for (int i = 0; i < 8; i++)
#pragma unroll
    for (int j = 0; j < 4; j++) acc[i][j] = zf;

  auto rdAhalf = [&](int par, int bufsel, int ph, int ks) {
    const char* base = ks ? pA1 : pA0;
#pragma unroll
    for (int dm = 0; dm < 2; dm++)
      af[par][dm][ks] = *(const bf16x8*)(base + bufsel * 32768 + (ph * 2 + dm) * 2048);
  };
  auto rdBhalf = [&](int bufsel, int ks) {
    const char* base = ks ? pB1 : pB0;
#pragma unroll
    for (int nj = 0; nj < 4; nj++)
      bfr[nj][ks] = *(const bf16x8*)(base + bufsel * 32768 + nj * 2048);
  };
  auto mfma8 = [&](int par, int ph, int ks) {
    __builtin_amdgcn_s_setprio(1);
#pragma unroll
    for (int dm = 0; dm < 2; dm++)
#pragma unroll
      for (int nj = 0; nj < 4; nj++)
        acc[ph * 2 + dm][nj] = __builtin_amdgcn_mfma_f32_16x16x32_bf16(
            af[par][dm][ks], bfr[nj][ks], acc[ph * 2 + dm][nj], 0, 0, 0);
    __builtin_amdgcn_s_setprio(0);
  };

  stA(0, 0, 0); stA(0, 1, 0); stB(0, 0, 0); stB(0, 1, 0);
  stB(1, 0, 1); stB(1, 1, 1);
  WAITV(4);
  __builtin_amdgcn_s_barrier();
  SCHEDB;
  rdAhalf(0, 0, 0, 0);
  rdBhalf(0, 0);
  rdAhalf(0, 0, 0, 1);
  rdBhalf(0, 1);

  for (int I = 0; I < NIT - 1; ++I) {
    const int t1 = 2 * I + 1, t2 = 2 * I + 2, t3 = 2 * I + 3;
#pragma unroll
    for (int gp = 0; gp < 8; ++gp) {
      __builtin_amdgcn_s_barrier();
      SCHEDB;
      { const int ng = (gp + 1) & 7; rdAhalf((gp + 1) & 1, ng >> 2, ng & 3, 0); }
      if (gp == 0)       stA(1, 0, t1);
      else if (gp == 1)  stA(1, 1, t1);
      else if (gp == 2)  stB(0, 0, t2);
      else if (gp == 3)  stB(0, 1, t2);
      else if (gp == 4)  stA(0, 0, t2);
      else if (gp == 5)  stA(0, 1, t2);
      else if (gp == 6)  stB(1, 0, t3);
      else               stB(1, 1, t3);
      if (gp == 0 || gp == 4) { WAITL(8); } else { WAITL(4); }
      SCHEDB;
      mfma8(gp & 1, gp & 3, 0);
      if (gp == 3)      rdBhalf(1, 0);
      else if (gp == 7) rdBhalf(0, 0);
      { const int ng = (gp + 1) & 7; rdAhalf((gp + 1) & 1, ng >> 2, ng & 3, 1); }
      if (gp == 3 || gp == 7) { WAITL(8); }
      else if (gp == 0 || gp == 4) { WAITL(6); }
      else { WAITL(4); }
      SCHEDB;
      mfma8(gp & 1, gp & 3, 1);
      if (gp == 3)      { rdBhalf(1, 1); SCHEDB; }
      else if (gp == 7) { rdBhalf(0, 1); SCHEDB; }
      if (gp == 2 || gp == 6) { WAITV(2); }
    }
  }
  {
    const int t1 = 2 * (NIT - 1) + 1;
#pragma unroll
    for (int gp = 0; gp < 8; ++gp) {
      __builtin_amdgcn_s_barrier();
      SCHEDB;
      if (gp < 7) { const int ng = gp + 1; rdAhalf((gp + 1) & 1, ng >> 2, ng & 3, 0); }
      if (gp == 0)       stA(1, 0, t1);
      else if (gp == 1)  stA(1, 1, t1);
      if (gp == 0 || gp == 4) { WAITL(8); }
      else if (gp == 7) { WAITL(2); }
      else { WAITL(4); }
      SCHEDB;
      mfma8(gp & 1, gp & 3, 0);
      if (gp == 3) rdBhalf(1, 0);
      if (gp < 7) { const int ng = gp + 1; rdAhalf((gp + 1) & 1, ng >> 2, ng & 3, 1); }
      if (gp == 3) { WAITL(8); }
      else if (gp == 0 || gp == 4) { WAITL(6); }
      else if (gp == 7) { WAITL(0); }
      else { WAITL(4); }
      SCHEDB;
      mfma8(gp & 1, gp & 3, 1);
      if (gp == 3) { rdBhalf(1, 1); SCHEDB; }
      if (gp == 2) { WAITV(0); }
    }
  }

  if constexpr (MODE == 1) {
#pragma unroll
    for (int mi = 0; mi < 8; mi++) {
      const int mrow = m0 + wr * 128 + mi * 16 + l4 * 4;
#pragma unroll
      for (int nj = 0; nj < 4; nj++) {
        const int col = n0 + wc * 64 + nj * 16 + l16;
        const float bi = bias[col];
#pragma unroll
        for (int jj = 0; jj < 4; jj++)
          outp[(size_t)(mrow + jj) * Ndim + col] = acc[mi][nj][jj] + bi;
      }
    }
  } else {
#pragma unroll
    for (int mi = 0; mi < 8; mi++) {
      const int mrow = m0 + wr * 128 + mi * 16 + l4 * 4;
      const int b = mrow >> 11, t0 = mrow & 2047;
#pragma unroll
      for (int nj = 0; nj < 4; nj++) {
        const int n = n0 + wc * 64 + nj * 16 + l16;
        const float bi = bias[n];
        const int part = n >> 11;          // 0=q 1=k 2=v
        const int hcol = n & 2047;
        const int h = hcol >> 7, d = hcol & 127;
        const int dm = d & 63;
        if (part == 2) {
          ushort4 vv;
          vv.x = f2bf(acc[mi][nj][0] + bi);
          vv.y = f2bf(acc[mi][nj][1] + bi);
          vv.z = f2bf(acc[mi][nj][2] + bi);
          vv.w = f2bf(acc[mi][nj][3] + bi);
          *(ushort4*)(vt + (((size_t)(b * NHn + h)) * HDn + d) * Tt + t0) = vv;
        } else {
#pragma unroll
          for (int jj = 0; jj < 4; jj++) {
            const int t = t0 + jj;
            float val = acc[mi][nj][jj] + bi;
            size_t didx = (((size_t)b * NHn + h) * Tt + t) * HDn + d;
            float partner = __shfl_xor(val, 1);
            float rh = (d & 1) ? partner : -partner;
            float cs = ctab[t * 64 + dm], sn = stab[t * 64 + dm];
            float o = val * cs + rh * sn;
            if (part == 0) q_r[didx] = f2bf(o * QSCALE2);
            else           k_r[didx] = f2bf(o);
          }
        }
      }
    }
  }
}

// ---------------- flash attention (causal) — R16 best config -------------
// Paired 512 grid, Ks dbuf + counted WAITV(4), Vs single, Ps padded 144B,
// two barriers/iter, T13 defer-max. NEW: softmax in exp2 domain (log2e
// folded into q at GEMM1 epilogue) — exp2f lowers to bare v_exp_f32,
// removing one VALU mul per exp on the critical path. Defer threshold 11
// (P bounded by 2^11, f32-accum safe; same headroom class as e^8).
__global__ __launch_bounds__(256, 2) void k_attn(
    const u16* __restrict__ q_r, const u16* __restrict__ k_r,
    const u16* __restrict__ vt, u16* __restrict__ y) {
  __shared__ u16 Ks[2][64 * 128];  // [buf][key][d], swizzled, 32KB
  __shared__ u16 Vs[128 * 64];     // V^T [d][key], swizzled, 16KB
  __shared__ u16 Ps[4][32 * 72];   // per-wave P, padded stride 144B, 18KB
  const int lin = blockIdx.x;           // 0..511
  const int swz = (lin & 7) * 64 + (lin >> 3);
  const int qpair = swz & 7;            // 0..7
  const int bh = swz >> 3;              // 0..63
  const int tid = threadIdx.x, w = tid >> 6, lane = tid & 63;
  const int l16 = lane & 15, l4 = lane >> 4;
  const int b = bh >> 4, h = bh & 15;

  const u16* kbase = k_r + (size_t)bh * Tt * HDn;
  const u16* vbase = vt + (size_t)bh * HDn * Tt;
  const f32x4 zf = {0.f, 0.f, 0.f, 0.f};

  auto stageK = [&](int buf, int j) {
    const char* ksrc = (const char*)(kbase + (size_t)j * 64 * HDn);
#pragma unroll
    for (int i = 0; i < 4; i++) {
      int op = tid * 16 + i * 4096;
      int ol = op ^ (((op >> 8) & 7) << 4);   // K rows are 256B
      gl_lds16(ksrc + ol, (char*)&Ks[buf][0] + op);
    }
  };
  auto stageV = [&](int j) {
    const char* vsrc = (const char*)(vbase + (size_t)j * 64);
#pragma unroll
    for (int i = 0; i < 4; i++) {
      int op = tid * 16 + i * 4096;
      int ol = op ^ (((op >> 7) & 7) << 4);   // V^T rows are 128B
      int row = ol >> 7, colb = ol & 127;
      gl_lds16(vsrc + (size_t)row * (Tt * 2) + colb, (char*)Vs + op);
    }
  };

#pragma unroll
  for (int qsel = 0; qsel < 2; ++qsel) {
    const int qt = qsel ? (15 - qpair) : qpair;

    const u16* qbase = q_r + ((size_t)bh * Tt + qt * 128 + w * 32) * HDn;
    bf16x8 qf[2][4];
#pragma unroll
    for (int mi = 0; mi < 2; mi++)
#pragma unroll
      for (int kc = 0; kc < 4; kc++)
        qf[mi][kc] = *(const bf16x8*)(qbase + (size_t)(mi * 16 + l16) * HDn + kc * 32 + l4 * 8);

    f32x4 acc_o[2][8];
#pragma unroll
    for (int mi = 0; mi < 2; mi++)
#pragma unroll
      for (int nf = 0; nf < 8; nf++) acc_o[mi][nf] = zf;
    float mrow[2][4], lrow[2][4];
#pragma unroll
    for (int mi = 0; mi < 2; mi++)
#pragma unroll
      for (int jj = 0; jj < 4; jj++) { mrow[mi][jj] = -1e30f; lrow[mi][jj] = 0.f; }

    const int ntiles = 2 * qt + 2;
    stageK(0, 0);
    __syncthreads();                 // K(0) landed + visible
    int cur = 0;

    for (int j = 0; j < ntiles; ++j) {
      const bool more = (j + 1 < ntiles);
      stageV(j);                     // 4 loads, consumed after mid barrier
      if (more) stageK(cur ^ 1, j + 1);  // 4 loads, consumed next iteration

      // ---- S = Q K^T from Ks[cur] (S already in log2 domain) ----
      f32x4 s[2][4];
#pragma unroll
      for (int mi = 0; mi < 2; mi++)
#pragma unroll
        for (int nj = 0; nj < 4; nj++) s[mi][nj] = zf;
#pragma unroll
      for (int kc = 0; kc < 4; kc++) {
        bf16x8 kf[4];
#pragma unroll
        for (int nj = 0; nj < 4; nj++) {
          int row = nj * 16 + l16;
          kf[nj] = *(const bf16x8*)((const char*)&Ks[cur][0] + row * 256 +
                                    ((kc * 64 + l4 * 16) ^ ((row & 7) << 4)));
        }
        __builtin_amdgcn_s_setprio(1);
#pragma unroll
        for (int mi = 0; mi < 2; mi++)
#pragma unroll
          for (int nj = 0; nj < 4; nj++)
            s[mi][nj] = __builtin_amdgcn_mfma_f32_16x16x32_bf16(qf[mi][kc], kf[nj], s[mi][nj], 0, 0, 0);
        __builtin_amdgcn_s_setprio(0);
      }

      // ---- online softmax in exp2 domain; defer-max (THR=11) ----
      const bool diag = (j >= 2 * qt);
#pragma unroll
      for (int mi = 0; mi < 2; mi++) {
#pragma unroll
        for (int jj = 0; jj < 4; jj++) {
          if (diag) {
            const int qrow = qt * 128 + w * 32 + mi * 16 + l4 * 4 + jj;
#pragma unroll
            for (int nj = 0; nj < 4; nj++) {
              const int key = j * 64 + nj * 16 + l16;
              if (key > qrow) s[mi][nj][jj] = -1e30f;
            }
          }
          float lm = fmaxf(fmaxf(s[mi][0][jj], s[mi][1][jj]), fmaxf(s[mi][2][jj], s[mi][3][jj]));
#pragma unroll
          for (int dd = 1; dd < 16; dd <<= 1) lm = fmaxf(lm, __shfl_xor(lm, dd));
          if (lm > mrow[mi][jj] + 11.0f) {  // defer-max: P bounded by 2^11
            const float sc = exp2f(mrow[mi][jj] - lm);
            mrow[mi][jj] = lm;
            lrow[mi][jj] *= sc;
#pragma unroll
            for (int nf = 0; nf < 8; nf++) acc_o[mi][nf][jj] *= sc;
          }
          float ps = 0.f;
#pragma unroll
          for (int nj = 0; nj < 4; nj++) {
            float p = exp2f(s[mi][nj][jj] - mrow[mi][jj]);
            s[mi][nj][jj] = p;
            ps += p;
          }
#pragma unroll
          for (int dd = 1; dd < 16; dd <<= 1) ps += __shfl_xor(ps, dd);
          lrow[mi][jj] += ps;
          const int prow = mi * 16 + l4 * 4 + jj;
#pragma unroll
          for (int nj = 0; nj < 4; nj++)
            Ps[w][prow * 72 + nj * 16 + l16] = f2bf(s[mi][nj][jj]);
        }
      }

      // ---- V(j) landed? (K(j+1)'s 4 loads may remain in flight) ----
      if (more) { WAITV(4); } else { WAITV(0); }
      __builtin_amdgcn_s_barrier();

      // ---- O += P V from Vs ----
#pragma unroll
      for (int kc = 0; kc < 2; kc++) {
        bf16x8 pf[2];
#pragma unroll
        for (int mi = 0; mi < 2; mi++)
          pf[mi] = *(const bf16x8*)((const char*)&Ps[w][0] + (mi * 16 + l16) * 144 + kc * 64 + l4 * 16);
        bf16x8 vf[8];
#pragma unroll
        for (int nf = 0; nf < 8; nf++) {
          int row = nf * 16 + l16;
          vf[nf] = *(const bf16x8*)((const char*)Vs + row * 128 +
                                    ((kc * 64 + l4 * 16) ^ ((row & 7) << 4)));
        }
        __builtin_amdgcn_s_setprio(1);
#pragma unroll
        for (int nf = 0; nf < 8; nf++)
#pragma unroll
          for (int mi = 0; mi < 2; mi++)
            acc_o[mi][nf] = __builtin_amdgcn_mfma_f32_16x16x32_bf16(pf[mi], vf[nf], acc_o[mi][nf], 0, 0, 0);
        __builtin_amdgcn_s_setprio(0);
      }
      __syncthreads();               // drains vmcnt(0): K(j+1) landed; reads done
      cur ^= 1;
    }

    // ---- epilogue for this q-tile ----
#pragma unroll
    for (int mi = 0; mi < 2; mi++) {
#pragma unroll
      for (int jj = 0; jj < 4; jj++) {
        const float rinv = 1.f / lrow[mi][jj];
        const int t = qt * 128 + w * 32 + mi * 16 + l4 * 4 + jj;
        u16* yrow = y + ((size_t)b * Tt + t) * Ccn + h * HDn;
#pragma unroll
        for (int nf = 0; nf < 8; nf++)
          yrow[nf * 16 + l16] = f2bf(acc_o[mi][nf][jj] * rinv);
      }
    }
    __syncthreads();                 // epilogue reads done before next qsel
  }
}

// ---------------- launcher ----------------

extern "C" void kernel_launch(void* const* d_in, const int* in_sizes, int n_in,
                              void* d_out, int out_size, void* d_ws, size_t ws_size,
                              hipStream_t stream) {
  const float* x     = (const float*)d_in[0];
  const float* Wqkv  = (const float*)d_in[1];
  const float* bqkv  = (const float*)d_in[2];
  const float* Wproj = (const float*)d_in[3];
  const float* bproj = (const float*)d_in[4];
  float* out = (float*)d_out;
  char* ws = (char*)d_ws;

  size_t off = 0;
  auto alloc = [&](size_t bytes) -> char* {
    char* p = ws + off;
    off += (bytes + 255) & ~(size_t)255;
    return p;
  };
  float* ctab  = (float*)alloc((size_t)Tt * 64 * sizeof(float));
  float* stab  = (float*)alloc((size_t)Tt * 64 * sizeof(float));
  u16* xb      = (u16*)alloc((size_t)MM * Ccn * 2);
  u16* WqkvT   = (u16*)alloc((size_t)NQKV * Ccn * 2);
  u16* WprojT  = (u16*)alloc((size_t)Ccn * Ccn * 2);
  u16* q_rb    = (u16*)alloc((size_t)MM * Ccn * 2);
  u16* k_rb    = (u16*)alloc((size_t)MM * Ccn * 2);
  u16* vtb     = (u16*)alloc((size_t)MM * Ccn * 2);   // V^T, written by GEMM1
  u16* ybuf    = (u16*)alloc((size_t)MM * Ccn * 2);

  k_prep<<<dim3(5632), 256, 0, stream>>>(x, xb, Wqkv, WqkvT, Wproj, WprojT, ctab, stab);

  k_gemm256<0><<<dim3((MM / 256) * (NQKV / 256)), 512, 0, stream>>>(
      xb, WqkvT, NQKV, NQKV / 256, bqkv, q_rb, k_rb, vtb, ctab, stab, nullptr);

  k_attn<<<dim3(512), 256, 0, stream>>>(q_rb, k_rb, vtb, ybuf);

  k_gemm256<1><<<dim3((MM / 256) * (Ccn / 256)), 512, 0, stream>>>(
      ybuf, WprojT, Ccn, Ccn / 256, bproj, nullptr, nullptr, nullptr, nullptr, nullptr, out);
}

// Round 18
// 439.722 us; speedup vs baseline: 1.0357x; 1.0357x over previous
//
#include <hip/hip_runtime.h>
#include <hip/hip_bf16.h>
#include <stdint.h>

#define DEV __device__ __forceinline__
#define WAITV(n) asm volatile("s_waitcnt vmcnt(" #n ")" ::: "memory")
#define WAITL(n) asm volatile("s_waitcnt lgkmcnt(" #n ")" ::: "memory")
#define SCHEDB __builtin_amdgcn_sched_barrier(0)

typedef __attribute__((ext_vector_type(4))) float f32x4;
typedef __attribute__((ext_vector_type(8))) short bf16x8;
typedef unsigned short u16;

constexpr int Bb = 4, Tt = 2048, Ccn = 2048, NHn = 16, HDn = 128;
constexpr int MM = Bb * Tt;          // 8192
constexpr int NQKV = 3 * Ccn;        // 6144
constexpr int KD = 2048;             // K dim for BOTH GEMMs
constexpr size_t K2 = (size_t)KD * 2;  // row stride bytes
constexpr size_t HKB = 128 * K2;       // half-tile row block bytes
// q scale folded with log2(e); softmax uses RAW v_exp_f32 via
// __builtin_amdgcn_exp2f (R17 lesson: exp2f() w/o fast-math lowers to the
// OCML precise path, ~8 extra VALU/call — VALUBusy went UP 32->37%).
constexpr float QSCALE2 = 0.08838834764831845f * 1.4426950408889634f;

DEV float fexp2(float x) { return __builtin_amdgcn_exp2f(x); }

DEV u16 f2bf(float f) {
  __hip_bfloat16 h = __float2bfloat16(f);
  return *reinterpret_cast<u16*>(&h);
}

DEV void gl_lds16(const void* g, void* l) {
  __builtin_amdgcn_global_load_lds(
      (const __attribute__((address_space(1))) void*)g,
      (__attribute__((address_space(3))) void*)l, 16, 0, 0);
}

// ---------------- merged prep kernel ----------------
__global__ void k_prep(const float* __restrict__ x, u16* __restrict__ xb,
                       const float* __restrict__ Wqkv, u16* __restrict__ WqkvT,
                       const float* __restrict__ Wproj, u16* __restrict__ WprojT,
                       float* __restrict__ ct, float* __restrict__ st) {
  __shared__ u16 tile[64][72];
  const int bid = blockIdx.x, tid = threadIdx.x;
  if (bid < 1024) {
    const int n4 = (MM * Ccn) >> 2;
    for (int idx = bid * 256 + tid; idx < n4; idx += 1024 * 256) {
      float4 v = ((const float4*)x)[idx];
      ushort4 o;
      o.x = f2bf(v.x); o.y = f2bf(v.y); o.z = f2bf(v.z); o.w = f2bf(v.w);
      ((ushort4*)xb)[idx] = o;
    }
  } else if (bid < 5120) {
    const float* in; u16* out; int NC, bx, by;
    if (bid < 4096) {
      int t = bid - 1024; in = Wqkv; out = WqkvT; NC = NQKV; bx = t % 96; by = t / 96;
    } else {
      int t = bid - 4096; in = Wproj; out = WprojT; NC = Ccn; bx = t & 31; by = t >> 5;
    }
    const int R = 2048;
    int tr = by * 64, tc = bx * 64;
    int r = tid >> 2, c = (tid & 3) * 16;
    const float* src = in + (size_t)(tr + r) * NC + tc + c;
#pragma unroll
    for (int i = 0; i < 16; i++) tile[r][c + i] = f2bf(src[i]);
    __syncthreads();
    u16* dst = out + (size_t)(tc + r) * R + tr + c;
#pragma unroll
    for (int i = 0; i < 16; i++) dst[i] = tile[c + i][r];
  } else {
    int idx = (bid - 5120) * 256 + tid;   // < 131072 = Tt*64
    int t = idx >> 6, j = idx & 63;
    float invf = expf(-(float)j * 0.14391157f);  // ln(10000)/64
    float a = (float)t * invf;
    ct[idx] = cosf(a);
    st[idx] = sinf(a);
  }
}

// ---------------- 256x256 8-phase GEMM, ks-split register pipeline -------
// (R11 config, 195us QKV / 48.6% MfmaUtil — frozen; MODE 0 epilogue uses
// QSCALE2 = QSCALE*log2e so attn softmax runs in exp2 domain)

template <int MODE>
__global__ __launch_bounds__(512, 2) void k_gemm256(
    const u16* __restrict__ A, const u16* __restrict__ Bt,
    int Ndim, int NBX,
    const float* __restrict__ bias,
    u16* __restrict__ q_r, u16* __restrict__ k_r, u16* __restrict__ vt,
    const float* __restrict__ ctab, const float* __restrict__ stab,
    float* __restrict__ outp) {
  __shared__ __align__(16) u16 SM[65536];   // 128KB: A 64KB | B 64KB
  const int tid = threadIdx.x;
  const int w = tid >> 6, lane = tid & 63;
  const int l16 = lane & 15, l4 = lane >> 4;
  const int wr = w >> 2, wc = w & 3;
  const int bid = blockIdx.x, nwg = gridDim.x;
  const int swz = (bid & 7) * (nwg >> 3) + (bid >> 3);   // XCD-aware
  const int by = swz / NBX, bx = swz % NBX;
  const int m0 = by * 256, n0 = bx * 256;
  constexpr int NT = KD >> 6;      // 32
  constexpr int NIT = NT >> 1;     // 16

  const int Mx = (l16 & 7) << 4;
  const int b6 = Mx & 64;
  const int lane_lo = l16 * 128 + ((l4 * 16) ^ (Mx & 48));
  const char* const pA0 = (const char*)SM + wr * 16384 + lane_lo + b6;
  const char* const pA1 = (const char*)SM + wr * 16384 + lane_lo + (64 - b6);
  const char* const pB0 = (const char*)SM + 65536 + (wc >> 1) * 16384 + (wc & 1) * 8192 + lane_lo + b6;
  const char* const pB1 = (const char*)SM + 65536 + (wc >> 1) * 16384 + (wc & 1) * 8192 + lane_lo + (64 - b6);

  uint32_t soff[2];
#pragma unroll
  for (int i = 0; i < 2; i++) {
    int op = i * 8192 + tid * 16;
    int ol = op ^ (((op >> 7) & 7) << 4);
    int row = ol >> 7, colb = ol & 127;
    soff[i] = (uint32_t)(row * (int)K2 + colb);
  }
  const char* const Ab = (const char*)A + (size_t)m0 * K2;
  const char* const Bbp = (const char*)Bt + (size_t)n0 * K2;
  char* const dstBase = (char*)SM;

  auto stA = [&](int buf, int half, int kt) {
#pragma unroll
    for (int i = 0; i < 2; i++)
      gl_lds16(Ab + (size_t)half * HKB + (size_t)kt * 128 + soff[i],
               dstBase + buf * 32768 + half * 16384 + i * 8192 + tid * 16);
  };
  auto stB = [&](int buf, int half, int kt) {
#pragma unroll
    for (int i = 0; i < 2; i++)
      gl_lds16(Bbp + (size_t)half * HKB + (size_t)kt * 128 + soff[i],
               dstBase + 65536 + buf * 32768 + half * 16384 + i * 8192 + tid * 16);
  };

  bf16x8 af[2][2][2];   // [parity][dm][ks]
  bf16x8 bfr[4][2];     // [nj][ks] single-buffered
  f32x4 acc[8][4];
  const f32x4 zf = {0.f, 0.f, 0.f, 0.f};
#pragma unroll
  for (int i = 0; i < 8; i++)
#pragma unroll
    for (int j = 0; j < 4; j++) acc[i][j] = zf;

  auto rdAhalf = [&](int par, int bufsel, int ph, int ks) {
    const char* base = ks ? pA1 : pA0;
#pragma unroll
    for (int dm = 0; dm < 2; dm++)
      af[par][dm][ks] = *(const bf16x8*)(base + bufsel * 32768 + (ph * 2 + dm) * 2048);
  };
  auto rdBhalf = [&](int bufsel, int ks) {
    const char* base = ks ? pB1 : pB0;
#pragma unroll
    for (int nj = 0; nj < 4; nj++)
      bfr[nj][ks] = *(const bf16x8*)(base + bufsel * 32768 + nj * 2048);
  };
  auto mfma8 = [&](int par, int ph, int ks) {
    __builtin_amdgcn_s_setprio(1);
#pragma unroll
    for (int dm = 0; dm < 2; dm++)
#pragma unroll
      for (int nj = 0; nj < 4; nj++)
        acc[ph * 2 + dm][nj] = __builtin_amdgcn_mfma_f32_16x16x32_bf16(
            af[par][dm][ks], bfr[nj][ks], acc[ph * 2 + dm][nj], 0, 0, 0);
    __builtin_amdgcn_s_setprio(0);
  };

  stA(0, 0, 0); stA(0, 1, 0); stB(0, 0, 0); stB(0, 1, 0);
  stB(1, 0, 1); stB(1, 1, 1);
  WAITV(4);
  __builtin_amdgcn_s_barrier();
  SCHEDB;
  rdAhalf(0, 0, 0, 0);
  rdBhalf(0, 0);
  rdAhalf(0, 0, 0, 1);
  rdBhalf(0, 1);

  for (int I = 0; I < NIT - 1; ++I) {
    const int t1 = 2 * I + 1, t2 = 2 * I + 2, t3 = 2 * I + 3;
#pragma unroll
    for (int gp = 0; gp < 8; ++gp) {
      __builtin_amdgcn_s_barrier();
      SCHEDB;
      { const int ng = (gp + 1) & 7; rdAhalf((gp + 1) & 1, ng >> 2, ng & 3, 0); }
      if (gp == 0)       stA(1, 0, t1);
      else if (gp == 1)  stA(1, 1, t1);
      else if (gp == 2)  stB(0, 0, t2);
      else if (gp == 3)  stB(0, 1, t2);
      else if (gp == 4)  stA(0, 0, t2);
      else if (gp == 5)  stA(0, 1, t2);
      else if (gp == 6)  stB(1, 0, t3);
      else               stB(1, 1, t3);
      if (gp == 0 || gp == 4) { WAITL(8); } else { WAITL(4); }
      SCHEDB;
      mfma8(gp & 1, gp & 3, 0);
      if (gp == 3)      rdBhalf(1, 0);
      else if (gp == 7) rdBhalf(0, 0);
      { const int ng = (gp + 1) & 7; rdAhalf((gp + 1) & 1, ng >> 2, ng & 3, 1); }
      if (gp == 3 || gp == 7) { WAITL(8); }
      else if (gp == 0 || gp == 4) { WAITL(6); }
      else { WAITL(4); }
      SCHEDB;
      mfma8(gp & 1, gp & 3, 1);
      if (gp == 3)      { rdBhalf(1, 1); SCHEDB; }
      else if (gp == 7) { rdBhalf(0, 1); SCHEDB; }
      if (gp == 2 || gp == 6) { WAITV(2); }
    }
  }
  {
    const int t1 = 2 * (NIT - 1) + 1;
#pragma unroll
    for (int gp = 0; gp < 8; ++gp) {
      __builtin_amdgcn_s_barrier();
      SCHEDB;
      if (gp < 7) { const int ng = gp + 1; rdAhalf((gp + 1) & 1, ng >> 2, ng & 3, 0); }
      if (gp == 0)       stA(1, 0, t1);
      else if (gp == 1)  stA(1, 1, t1);
      if (gp == 0 || gp == 4) { WAITL(8); }
      else if (gp == 7) { WAITL(2); }
      else { WAITL(4); }
      SCHEDB;
      mfma8(gp & 1, gp & 3, 0);
      if (gp == 3) rdBhalf(1, 0);
      if (gp < 7) { const int ng = gp + 1; rdAhalf((gp + 1) & 1, ng >> 2, ng & 3, 1); }
      if (gp == 3) { WAITL(8); }
      else if (gp == 0 || gp == 4) { WAITL(6); }
      else if (gp == 7) { WAITL(0); }
      else { WAITL(4); }
      SCHEDB;
      mfma8(gp & 1, gp & 3, 1);
      if (gp == 3) { rdBhalf(1, 1); SCHEDB; }
      if (gp == 2) { WAITV(0); }
    }
  }

  if constexpr (MODE == 1) {
#pragma unroll
    for (int mi = 0; mi < 8; mi++) {
      const int mrow = m0 + wr * 128 + mi * 16 + l4 * 4;
#pragma unroll
      for (int nj = 0; nj < 4; nj++) {
        const int col = n0 + wc * 64 + nj * 16 + l16;
        const float bi = bias[col];
#pragma unroll
        for (int jj = 0; jj < 4; jj++)
          outp[(size_t)(mrow + jj) * Ndim + col] = acc[mi][nj][jj] + bi;
      }
    }
  } else {
#pragma unroll
    for (int mi = 0; mi < 8; mi++) {
      const int mrow = m0 + wr * 128 + mi * 16 + l4 * 4;
      const int b = mrow >> 11, t0 = mrow & 2047;
#pragma unroll
      for (int nj = 0; nj < 4; nj++) {
        const int n = n0 + wc * 64 + nj * 16 + l16;
        const float bi = bias[n];
        const int part = n >> 11;          // 0=q 1=k 2=v
        const int hcol = n & 2047;
        const int h = hcol >> 7, d = hcol & 127;
        const int dm = d & 63;
        if (part == 2) {
          ushort4 vv;
          vv.x = f2bf(acc[mi][nj][0] + bi);
          vv.y = f2bf(acc[mi][nj][1] + bi);
          vv.z = f2bf(acc[mi][nj][2] + bi);
          vv.w = f2bf(acc[mi][nj][3] + bi);
          *(ushort4*)(vt + (((size_t)(b * NHn + h)) * HDn + d) * Tt + t0) = vv;
        } else {
#pragma unroll
          for (int jj = 0; jj < 4; jj++) {
            const int t = t0 + jj;
            float val = acc[mi][nj][jj] + bi;
            size_t didx = (((size_t)b * NHn + h) * Tt + t) * HDn + d;
            float partner = __shfl_xor(val, 1);
            float rh = (d & 1) ? partner : -partner;
            float cs = ctab[t * 64 + dm], sn = stab[t * 64 + dm];
            float o = val * cs + rh * sn;
            if (part == 0) q_r[didx] = f2bf(o * QSCALE2);
            else           k_r[didx] = f2bf(o);
          }
        }
      }
    }
  }
}

// ---------------- flash attention (causal) — R16 best config -------------
// Paired 512 grid, Ks dbuf + counted WAITV(4), Vs single, Ps padded 144B,
// two barriers/iter, T13 defer-max (THR=11 in log2 domain). Softmax in
// exp2 domain via RAW __builtin_amdgcn_exp2f (bare v_exp_f32; flushes the
// masked -1e30 inputs to 0 as desired).
__global__ __launch_bounds__(256, 2) void k_attn(
    const u16* __restrict__ q_r, const u16* __restrict__ k_r,
    const u16* __restrict__ vt, u16* __restrict__ y) {
  __shared__ u16 Ks[2][64 * 128];  // [buf][key][d], swizzled, 32KB
  __shared__ u16 Vs[128 * 64];     // V^T [d][key], swizzled, 16KB
  __shared__ u16 Ps[4][32 * 72];   // per-wave P, padded stride 144B, 18KB
  const int lin = blockIdx.x;           // 0..511
  const int swz = (lin & 7) * 64 + (lin >> 3);
  const int qpair = swz & 7;            // 0..7
  const int bh = swz >> 3;              // 0..63
  const int tid = threadIdx.x, w = tid >> 6, lane = tid & 63;
  const int l16 = lane & 15, l4 = lane >> 4;
  const int b = bh >> 4, h = bh & 15;

  const u16* kbase = k_r + (size_t)bh * Tt * HDn;
  const u16* vbase = vt + (size_t)bh * HDn * Tt;
  const f32x4 zf = {0.f, 0.f, 0.f, 0.f};

  auto stageK = [&](int buf, int j) {
    const char* ksrc = (const char*)(kbase + (size_t)j * 64 * HDn);
#pragma unroll
    for (int i = 0; i < 4; i++) {
      int op = tid * 16 + i * 4096;
      int ol = op ^ (((op >> 8) & 7) << 4);   // K rows are 256B
      gl_lds16(ksrc + ol, (char*)&Ks[buf][0] + op);
    }
  };
  auto stageV = [&](int j) {
    const char* vsrc = (const char*)(vbase + (size_t)j * 64);
#pragma unroll
    for (int i = 0; i < 4; i++) {
      int op = tid * 16 + i * 4096;
      int ol = op ^ (((op >> 7) & 7) << 4);   // V^T rows are 128B
      int row = ol >> 7, colb = ol & 127;
      gl_lds16(vsrc + (size_t)row * (Tt * 2) + colb, (char*)Vs + op);
    }
  };

#pragma unroll
  for (int qsel = 0; qsel < 2; ++qsel) {
    const int qt = qsel ? (15 - qpair) : qpair;

    const u16* qbase = q_r + ((size_t)bh * Tt + qt * 128 + w * 32) * HDn;
    bf16x8 qf[2][4];
#pragma unroll
    for (int mi = 0; mi < 2; mi++)
#pragma unroll
      for (int kc = 0; kc < 4; kc++)
        qf[mi][kc] = *(const bf16x8*)(qbase + (size_t)(mi * 16 + l16) * HDn + kc * 32 + l4 * 8);

    f32x4 acc_o[2][8];
#pragma unroll
    for (int mi = 0; mi < 2; mi++)
#pragma unroll
      for (int nf = 0; nf < 8; nf++) acc_o[mi][nf] = zf;
    float mrow[2][4], lrow[2][4];
#pragma unroll
    for (int mi = 0; mi < 2; mi++)
#pragma unroll
      for (int jj = 0; jj < 4; jj++) { mrow[mi][jj] = -1e30f; lrow[mi][jj] = 0.f; }

    const int ntiles = 2 * qt + 2;
    stageK(0, 0);
    __syncthreads();                 // K(0) landed + visible
    int cur = 0;

    for (int j = 0; j < ntiles; ++j) {
      const bool more = (j + 1 < ntiles);
      stageV(j);                     // 4 loads, consumed after mid barrier
      if (more) stageK(cur ^ 1, j + 1);  // 4 loads, consumed next iteration

      // ---- S = Q K^T from Ks[cur] (S already in log2 domain) ----
      f32x4 s[2][4];
#pragma unroll
      for (int mi = 0; mi < 2; mi++)
#pragma unroll
        for (int nj = 0; nj < 4; nj++) s[mi][nj] = zf;
#pragma unroll
      for (int kc = 0; kc < 4; kc++) {
        bf16x8 kf[4];
#pragma unroll
        for (int nj = 0; nj < 4; nj++) {
          int row = nj * 16 + l16;
          kf[nj] = *(const bf16x8*)((const char*)&Ks[cur][0] + row * 256 +
                                    ((kc * 64 + l4 * 16) ^ ((row & 7) << 4)));
        }
        __builtin_amdgcn_s_setprio(1);
#pragma unroll
        for (int mi = 0; mi < 2; mi++)
#pragma unroll
          for (int nj = 0; nj < 4; nj++)
            s[mi][nj] = __builtin_amdgcn_mfma_f32_16x16x32_bf16(qf[mi][kc], kf[nj], s[mi][nj], 0, 0, 0);
        __builtin_amdgcn_s_setprio(0);
      }

      // ---- online softmax, exp2 domain, raw v_exp_f32; defer-max THR=11 ----
      const bool diag = (j >= 2 * qt);
#pragma unroll
      for (int mi = 0; mi < 2; mi++) {
#pragma unroll
        for (int jj = 0; jj < 4; jj++) {
          if (diag) {
            const int qrow = qt * 128 + w * 32 + mi * 16 + l4 * 4 + jj;
#pragma unroll
            for (int nj = 0; nj < 4; nj++) {
              const int key = j * 64 + nj * 16 + l16;
              if (key > qrow) s[mi][nj][jj] = -1e30f;
            }
          }
          float lm = fmaxf(fmaxf(s[mi][0][jj], s[mi][1][jj]), fmaxf(s[mi][2][jj], s[mi][3][jj]));
#pragma unroll
          for (int dd = 1; dd < 16; dd <<= 1) lm = fmaxf(lm, __shfl_xor(lm, dd));
          if (lm > mrow[mi][jj] + 11.0f) {  // defer-max: P bounded by 2^11
            const float sc = fexp2(mrow[mi][jj] - lm);
            mrow[mi][jj] = lm;
            lrow[mi][jj] *= sc;
#pragma unroll
            for (int nf = 0; nf < 8; nf++) acc_o[mi][nf][jj] *= sc;
          }
          float ps = 0.f;
#pragma unroll
          for (int nj = 0; nj < 4; nj++) {
            float p = fexp2(s[mi][nj][jj] - mrow[mi][jj]);
            s[mi][nj][jj] = p;
            ps += p;
          }
#pragma unroll
          for (int dd = 1; dd < 16; dd <<= 1) ps += __shfl_xor(ps, dd);
          lrow[mi][jj] += ps;
          const int prow = mi * 16 + l4 * 4 + jj;
#pragma unroll
          for (int nj = 0; nj < 4; nj++)
            Ps[w][prow * 72 + nj * 16 + l16] = f2bf(s[mi][nj][jj]);
        }
      }

      // ---- V(j) landed? (K(j+1)'s 4 loads may remain in flight) ----
      if (more) { WAITV(4); } else { WAITV(0); }
      __builtin_amdgcn_s_barrier();

      // ---- O += P V from Vs ----
#pragma unroll
      for (int kc = 0; kc < 2; kc++) {
        bf16x8 pf[2];
#pragma unroll
        for (int mi = 0; mi < 2; mi++)
          pf[mi] = *(const bf16x8*)((const char*)&Ps[w][0] + (mi * 16 + l16) * 144 + kc * 64 + l4 * 16);
        bf16x8 vf[8];
#pragma unroll
        for (int nf = 0; nf < 8; nf++) {
          int row = nf * 16 + l16;
          vf[nf] = *(const bf16x8*)((const char*)Vs + row * 128 +
                                    ((kc * 64 + l4 * 16) ^ ((row & 7) << 4)));
        }
        __builtin_amdgcn_s_setprio(1);
#pragma unroll
        for (int nf = 0; nf < 8; nf++)
#pragma unroll
          for (int mi = 0; mi < 2; mi++)
            acc_o[mi][nf] = __builtin_amdgcn_mfma_f32_16x16x32_bf16(pf[mi], vf[nf], acc_o[mi][nf], 0, 0, 0);
        __builtin_amdgcn_s_setprio(0);
      }
      __syncthreads();               // drains vmcnt(0): K(j+1) landed; reads done
      cur ^= 1;
    }

    // ---- epilogue for this q-tile ----
#pragma unroll
    for (int mi = 0; mi < 2; mi++) {
#pragma unroll
      for (int jj = 0; jj < 4; jj++) {
        const float rinv = 1.f / lrow[mi][jj];
        const int t = qt * 128 + w * 32 + mi * 16 + l4 * 4 + jj;
        u16* yrow = y + ((size_t)b * Tt + t) * Ccn + h * HDn;
#pragma unroll
        for (int nf = 0; nf < 8; nf++)
          yrow[nf * 16 + l16] = f2bf(acc_o[mi][nf][jj] * rinv);
      }
    }
    __syncthreads();                 // epilogue reads done before next qsel
  }
}

// ---------------- launcher ----------------

extern "C" void kernel_launch(void* const* d_in, const int* in_sizes, int n_in,
                              void* d_out, int out_size, void* d_ws, size_t ws_size,
                              hipStream_t stream) {
  const float* x     = (const float*)d_in[0];
  const float* Wqkv  = (const float*)d_in[1];
  const float* bqkv  = (const float*)d_in[2];
  const float* Wproj = (const float*)d_in[3];
  const float* bproj = (const float*)d_in[4];
  float* out = (float*)d_out;
  char* ws = (char*)d_ws;

  size_t off = 0;
  auto alloc = [&](size_t bytes) -> char* {
    char* p = ws + off;
    off += (bytes + 255) & ~(size_t)255;
    return p;
  };
  float* ctab  = (float*)alloc((size_t)Tt * 64 * sizeof(float));
  float* stab  = (float*)alloc((size_t)Tt * 64 * sizeof(float));
  u16* xb      = (u16*)alloc((size_t)MM * Ccn * 2);
  u16* WqkvT   = (u16*)alloc((size_t)NQKV * Ccn * 2);
  u16* WprojT  = (u16*)alloc((size_t)Ccn * Ccn * 2);
  u16* q_rb    = (u16*)alloc((size_t)MM * Ccn * 2);
  u16* k_rb    = (u16*)alloc((size_t)MM * Ccn * 2);
  u16* vtb     = (u16*)alloc((size_t)MM * Ccn * 2);   // V^T, written by GEMM1
  u16* ybuf    = (u16*)alloc((size_t)MM * Ccn * 2);

  k_prep<<<dim3(5632), 256, 0, stream>>>(x, xb, Wqkv, WqkvT, Wproj, WprojT, ctab, stab);

  k_gemm256<0><<<dim3((MM / 256) * (NQKV / 256)), 512, 0, stream>>>(
      xb, WqkvT, NQKV, NQKV / 256, bqkv, q_rb, k_rb, vtb, ctab, stab, nullptr);

  k_attn<<<dim3(512), 256, 0, stream>>>(q_rb, k_rb, vtb, ybuf);

  k_gemm256<1><<<dim3((MM / 256) * (Ccn / 256)), 512, 0, stream>>>(
      ybuf, WprojT, Ccn, Ccn / 256, bproj, nullptr, nullptr, nullptr, nullptr, nullptr, out);
}